// Round 5
// baseline (303.149 us; speedup 1.0000x reference)
//
#include <hip/hip_runtime.h>
#include <hip/hip_bf16.h>
#include <math.h>

#define EPS 1e-5f

static constexpr int Bb = 8;
static constexpr int Ss = 8192;
static constexpr int Dd = 1024;      // QD = KD = AD
static constexpr int NW = 64;        // pass blocks per batch
static constexpr int NWv = NW * 4;   // wave partials per batch (256)
static constexpr int TOK = Ss / NWv; // tokens per wave (32)
static constexpr int NCH = 128;      // qk chunk count
static constexpr int RC = Dd / NCH;  // rows per chunk (8)

// ---------- helpers ----------

__device__ __forceinline__ float blk_reduce(float v, bool ismax, volatile float* lds) {
#pragma unroll
  for (int msk = 32; msk; msk >>= 1) {
    float o = __shfl_xor(v, msk);
    v = ismax ? fmaxf(v, o) : (v + o);
  }
  int w = threadIdx.x >> 6;
  __syncthreads();
  if ((threadIdx.x & 63) == 0) lds[w] = v;
  __syncthreads();
  return ismax ? fmaxf(fmaxf(lds[0], lds[1]), fmaxf(lds[2], lds[3]))
               : (lds[0] + lds[1] + lds[2] + lds[3]);
}

__device__ __forceinline__ float wred_max(float v) {
#pragma unroll
  for (int msk = 32; msk; msk >>= 1) v = fmaxf(v, __shfl_xor(v, msk));
  return v;
}

__device__ __forceinline__ float wred_sum(float v) {
#pragma unroll
  for (int msk = 32; msk; msk >>= 1) v += __shfl_xor(v, msk);
  return v;
}

__device__ __forceinline__ float quantf(float x, float c) {
  return fminf(fmaxf(rintf(x * c), -128.f), 127.f);
}

__device__ __forceinline__ float ternf(float w, float s) {
  return fminf(fmaxf(rintf(w / s), -1.f), 1.f);
}

__device__ __forceinline__ float4 tern4(float4 w, float s) {
  return make_float4(ternf(w.x, s), ternf(w.y, s), ternf(w.z, s), ternf(w.w, s));
}

__device__ __forceinline__ float4 quant4(float4 v, float c) {
  return make_float4(quantf(v.x, c), quantf(v.y, c), quantf(v.z, c), quantf(v.w, c));
}

__device__ __forceinline__ float dot4(float4 a, float4 b) {
  return a.x * b.x + a.y * b.y + a.z * b.z + a.w * b.w;
}

// grid-wide spin barrier; grid must be co-resident (<= 256 blocks, modest LDS)
__device__ __forceinline__ void gridspin(int* c, int target) {
  __syncthreads();
  if (threadIdx.x == 0) {
    __threadfence();
    atomicAdd(c, 1);
    while (__hip_atomic_load(c, __ATOMIC_ACQUIRE, __HIP_MEMORY_SCOPE_AGENT) < target)
      __builtin_amdgcn_s_sleep(8);
  }
  __syncthreads();
  __threadfence();
}

// ---------- K1: prologue (scales + q-GEMV + qk), 256 blocks ----------

__global__ __launch_bounds__(256) void k_pre(
    const float* __restrict__ query,
    const float* __restrict__ w_q, const float* __restrict__ b_q,
    const float* __restrict__ w_k, const float* __restrict__ b_k,
    const float* __restrict__ w_v, const float* __restrict__ w_c,
    double* __restrict__ part, float* __restrict__ scales,
    float* __restrict__ q, float* __restrict__ qkp,
    float* __restrict__ qk, float* __restrict__ qdotbk, int* __restrict__ cnt)
{
  __shared__ float red[4];
  __shared__ double sred[256];
  __shared__ float qs[Bb * Dd];   // 32 KB quantized query
  __shared__ float gsh[8];
  __shared__ float ssh[4];
  int tid = threadIdx.x;

  // --- Phase A: weight abs-sum partials ---
  {
    int seg = blockIdx.x >> 6, blk = blockIdx.x & 63;
    const float* w = seg == 0 ? w_q : seg == 1 ? w_k : seg == 2 ? w_v : w_c;
    int n4 = (seg == 3 ? (1024 * 2048) : (1024 * 1024)) >> 2;
    const float4* w4 = (const float4*)w;
    double acc = 0.0;
    for (int i = blk * 256 + tid; i < n4; i += 64 * 256) {
      float4 v = w4[i];
      acc += (double)fabsf(v.x) + (double)fabsf(v.y)
           + (double)fabsf(v.z) + (double)fabsf(v.w);
    }
    sred[tid] = acc;
    __syncthreads();
    for (int s = 128; s > 0; s >>= 1) {
      if (tid < s) sred[tid] += sred[tid + s];
      __syncthreads();
    }
    if (tid == 0) part[blockIdx.x] = sred[0];
  }
  gridspin(&cnt[0], 256);

  // --- Phase B: every block computes all 4 scales (deterministic, identical) ---
  if (tid < 4) {
    double s = 0.0;
    for (int i = 0; i < 64; i++) s += part[tid * 64 + i];
    double n = (tid == 3) ? 2097152.0 : 1048576.0;
    ssh[tid] = (float)(s / n) + EPS;
    if (blockIdx.x == 0) scales[tid] = ssh[tid];
  }
  __syncthreads();

  // --- Phase C: quantize query (redundant per block) + batch-shared q GEMV ---
  for (int b = 0; b < 8; b++) {
    float4 v = ((const float4*)(query + (size_t)b * Dd))[tid];
    float am = fmaxf(fmaxf(fabsf(v.x), fabsf(v.y)), fmaxf(fabsf(v.z), fabsf(v.w)));
    am = blk_reduce(am, true, red);
    float g = am + EPS;
    ((float4*)qs)[b * 256 + tid] = quant4(v, 127.0f / g);
    if (tid == 0) gsh[b] = g;
  }
  __syncthreads();
  {
    float s0 = ssh[0];
    int wv = tid >> 6, lane = tid & 63;
    int o = blockIdx.x * 4 + wv;
    const float4* wr = (const float4*)(w_q + (size_t)o * Dd);
    float acc[8] = {0, 0, 0, 0, 0, 0, 0, 0};
#pragma unroll
    for (int i = 0; i < 4; i++) {
      float4 t4 = tern4(wr[i * 64 + lane], s0);
#pragma unroll
      for (int b = 0; b < 8; b++)
        acc[b] += dot4(((float4*)qs)[b * 256 + i * 64 + lane], t4);
    }
#pragma unroll
    for (int b = 0; b < 8; b++) acc[b] = wred_sum(acc[b]);
    if (lane == 0) {
      float bq = b_q[o];
#pragma unroll
      for (int b = 0; b < 8; b++)
        q[(size_t)b * Dd + o] = s0 * (gsh[b] / 127.0f) * acc[b] + bq;
    }
  }
  gridspin(&cnt[1], 256);

  // --- Phase D: qk chunk partials (blocks 0..NCH-1) ---
  float s1 = ssh[1];
  if (blockIdx.x < NCH) {
    __shared__ float qs2[Bb * RC];
    int ch = blockIdx.x, a0 = ch * RC;
    if (tid < Bb * RC) {
      int b = tid / RC, a = tid - b * RC;
      qs2[tid] = q[(size_t)b * Dd + a0 + a];
    }
    __syncthreads();
    float4 acc4[8];
#pragma unroll
    for (int b = 0; b < 8; b++) acc4[b] = make_float4(0, 0, 0, 0);
    const float4* Wr = (const float4*)(w_k + (size_t)a0 * Dd);
    for (int i = 0; i < RC; i++) {
      float4 t4 = tern4(Wr[(size_t)i * 256 + tid], s1);
#pragma unroll
      for (int b = 0; b < 8; b++) {
        float qb = qs2[b * RC + i];
        acc4[b].x += qb * t4.x; acc4[b].y += qb * t4.y;
        acc4[b].z += qb * t4.z; acc4[b].w += qb * t4.w;
      }
    }
#pragma unroll
    for (int b = 0; b < 8; b++)
      ((float4*)qkp)[((size_t)ch * Bb + b) * 256 + tid] = acc4[b];
  }
  gridspin(&cnt[2], 256);

  // --- Phase E: combine qk partials (blocks 0..63) + q.b_k ---
  if (blockIdx.x < 64) {
    __shared__ float4 lred[8][32];
    int b = blockIdx.x >> 3, dc = blockIdx.x & 7;
    int col = tid & 31, kg = tid >> 5;
    int d4 = dc * 32 + col;
    float4 a = make_float4(0, 0, 0, 0);
    for (int k = kg * 16; k < kg * 16 + 16; k++) {
      float4 p = ((const float4*)qkp)[((size_t)k * Bb + b) * 256 + d4];
      a.x += p.x; a.y += p.y; a.z += p.z; a.w += p.w;
    }
    lred[kg][col] = a;
    __syncthreads();
    if (kg == 0) {
      float4 t = lred[0][col];
#pragma unroll
      for (int g = 1; g < 8; g++) {
        float4 v = lred[g][col];
        t.x += v.x; t.y += v.y; t.z += v.z; t.w += v.w;
      }
      ((float4*)qk)[(size_t)b * 256 + d4] =
          make_float4(s1 * t.x, s1 * t.y, s1 * t.z, s1 * t.w);
    } else if (dc == 0 && tid >= 192) {
      int lane = tid - 192;
      float p = 0.f;
      for (int a2 = lane; a2 < Dd; a2 += 64) p += q[(size_t)b * Dd + a2] * b_k[a2];
      p = wred_sum(p);
      if (lane == 0) qdotbk[b] = p;
    }
  }
}

// ---------- K2: fused streaming pass, one WAVE per token, defer-max ----------

__global__ __launch_bounds__(256) void k_pass(
    const float* __restrict__ X, const float* __restrict__ qk,
    const float* __restrict__ qdotbk,
    float* __restrict__ m_part, float* __restrict__ l_part,
    float* __restrict__ t_part)
{
  int b    = blockIdx.x >> 6;
  int wg   = blockIdx.x & 63;
  int wv   = threadIdx.x >> 6;
  int lane = threadIdx.x & 63;
  int widx = wg * 4 + wv;
  int s0   = widx * TOK;

  const float4* qkb = (const float4*)(qk + (size_t)b * Dd);
  float4 qv0 = qkb[lane], qv1 = qkb[64 + lane], qv2 = qkb[128 + lane], qv3 = qkb[192 + lane];
  float qb = qdotbk[b];
  const float4* Xw = (const float4*)(X + ((size_t)b * Ss + s0) * Dd);

  float m = -INFINITY, l = 0.f;
  float4 a0 = make_float4(0,0,0,0), a1 = a0, a2 = a0, a3 = a0;

  float4 x0 = Xw[lane], x1 = Xw[64 + lane], x2 = Xw[128 + lane], x3 = Xw[192 + lane];
  for (int i = 0; i < TOK; i++) {
    size_t nb = (size_t)((i + 1 < TOK) ? i + 1 : i) * 256;
    float4 n0 = Xw[nb + lane], n1 = Xw[nb + 64 + lane],
           n2 = Xw[nb + 128 + lane], n3 = Xw[nb + 192 + lane];

    float am = fmaxf(
      fmaxf(fmaxf(fmaxf(fabsf(x0.x), fabsf(x0.y)), fmaxf(fabsf(x0.z), fabsf(x0.w))),
            fmaxf(fmaxf(fabsf(x1.x), fabsf(x1.y)), fmaxf(fabsf(x1.z), fabsf(x1.w)))),
      fmaxf(fmaxf(fmaxf(fabsf(x2.x), fabsf(x2.y)), fmaxf(fabsf(x2.z), fabsf(x2.w))),
            fmaxf(fmaxf(fabsf(x3.x), fabsf(x3.y)), fmaxf(fabsf(x3.z), fabsf(x3.w)))));
    am = wred_max(am);
    float g = am + EPS;
    float c = 127.0f / g;
    float gi = g / 127.0f;

    float q00 = quantf(x0.x, c), q01 = quantf(x0.y, c), q02 = quantf(x0.z, c), q03 = quantf(x0.w, c);
    float q10 = quantf(x1.x, c), q11 = quantf(x1.y, c), q12 = quantf(x1.z, c), q13 = quantf(x1.w, c);
    float q20 = quantf(x2.x, c), q21 = quantf(x2.y, c), q22 = quantf(x2.z, c), q23 = quantf(x2.w, c);
    float q30 = quantf(x3.x, c), q31 = quantf(x3.y, c), q32 = quantf(x3.z, c), q33 = quantf(x3.w, c);

    float dt = q00 * qv0.x + q01 * qv0.y + q02 * qv0.z + q03 * qv0.w
             + q10 * qv1.x + q11 * qv1.y + q12 * qv1.z + q13 * qv1.w
             + q20 * qv2.x + q21 * qv2.y + q22 * qv2.z + q23 * qv2.w
             + q30 * qv3.x + q31 * qv3.y + q32 * qv3.z + q33 * qv3.w;
    dt = wred_sum(dt);

    float score = (dt * gi + qb) * 0.03125f;   // / sqrt(1024)
    if (score <= m) {                          // wave-uniform
      float p  = expf(score - m);
      l += p;
      float cf = p * gi;
      a0.x += cf * q00; a0.y += cf * q01; a0.z += cf * q02; a0.w += cf * q03;
      a1.x += cf * q10; a1.y += cf * q11; a1.z += cf * q12; a1.w += cf * q13;
      a2.x += cf * q20; a2.y += cf * q21; a2.z += cf * q22; a2.w += cf * q23;
      a3.x += cf * q30; a3.y += cf * q31; a3.z += cf * q32; a3.w += cf * q33;
    } else {
      float scl = expf(m - score);
      l = l * scl + 1.0f;
      float cf = gi;
      a0.x = a0.x * scl + cf * q00; a0.y = a0.y * scl + cf * q01;
      a0.z = a0.z * scl + cf * q02; a0.w = a0.w * scl + cf * q03;
      a1.x = a1.x * scl + cf * q10; a1.y = a1.y * scl + cf * q11;
      a1.z = a1.z * scl + cf * q12; a1.w = a1.w * scl + cf * q13;
      a2.x = a2.x * scl + cf * q20; a2.y = a2.y * scl + cf * q21;
      a2.z = a2.z * scl + cf * q22; a2.w = a2.w * scl + cf * q23;
      a3.x = a3.x * scl + cf * q30; a3.y = a3.y * scl + cf * q31;
      a3.z = a3.z * scl + cf * q32; a3.w = a3.w * scl + cf * q33;
      m = score;
    }
    x0 = n0; x1 = n1; x2 = n2; x3 = n3;
  }

  size_t pidx = (size_t)b * NWv + widx;
  float4* tpw = (float4*)t_part + (size_t)pidx * 256;
  tpw[lane] = a0; tpw[64 + lane] = a1; tpw[128 + lane] = a2; tpw[192 + lane] = a3;
  if (lane == 0) { m_part[pidx] = m; l_part[pidx] = l; }
}

// ---------- K3: epilogue (combine + v-GEMV + final GEMV), 256 blocks ----------

__global__ __launch_bounds__(256) void k_post(
    const float* __restrict__ query,
    const float* __restrict__ m_part, const float* __restrict__ l_part,
    const float* __restrict__ t_part,
    const float* __restrict__ w_v, const float* __restrict__ b_v,
    const float* __restrict__ w_c, const float* __restrict__ b_c,
    const float* __restrict__ scales,
    float* __restrict__ t32, float* __restrict__ ML,
    float* __restrict__ tvec, float* __restrict__ ctx,
    float* __restrict__ out, int* __restrict__ cnt)
{
  __shared__ float red[4];
  __shared__ float cs[16384];   // 64 KB: phase3 t rows / phase4 quantized [query,ctx]
  __shared__ float gsh[8];
  int tid = threadIdx.x;

  // --- Phase 1: weighted partial sums (b,k): 8 partials each ---
  {
    int b = blockIdx.x >> 5, k = blockIdx.x & 31;
    float mi = m_part[(size_t)b * NWv + tid];
    float M = blk_reduce(mi, true, red);
    float li = l_part[(size_t)b * NWv + tid] * expf(mi - M);
    float L = blk_reduce(li, false, red);
    float4 acc = make_float4(0, 0, 0, 0);
    for (int i = 0; i < 8; i++) {
      size_t pi = (size_t)b * NWv + k * 8 + i;
      float w = expf(m_part[pi] - M);
      float4 tp = ((const float4*)t_part)[pi * 256 + tid];
      acc.x += w * tp.x; acc.y += w * tp.y; acc.z += w * tp.z; acc.w += w * tp.w;
    }
    ((float4*)t32)[((size_t)(b * 32 + k)) * 256 + tid] = acc;
    if (k == 0 && tid == 0) { ML[b * 2] = M; ML[b * 2 + 1] = L; }
  }
  gridspin(&cnt[3], 256);

  // --- Phase 2: reduce 32 -> 1, normalize -> tvec (blocks 0..63) ---
  if (blockIdx.x < 64) {
    __shared__ float4 lred[8][32];
    int b = blockIdx.x >> 3, dc = blockIdx.x & 7;
    int col = tid & 31, kg = tid >> 5;
    int d4 = dc * 32 + col;
    float4 a = make_float4(0, 0, 0, 0);
    for (int kk = kg * 4; kk < kg * 4 + 4; kk++) {
      float4 v = ((const float4*)t32)[((size_t)(b * 32 + kk)) * 256 + d4];
      a.x += v.x; a.y += v.y; a.z += v.z; a.w += v.w;
    }
    lred[kg][col] = a;
    __syncthreads();
    if (kg == 0) {
      float4 s = lred[0][col];
#pragma unroll
      for (int g = 1; g < 8; g++) {
        float4 v = lred[g][col];
        s.x += v.x; s.y += v.y; s.z += v.z; s.w += v.w;
      }
      float invL = 1.0f / ML[b * 2 + 1];
      ((float4*)tvec)[(size_t)b * 256 + d4] =
          make_float4(s.x * invL, s.y * invL, s.z * invL, s.w * invL);
    }
  }
  gridspin(&cnt[4], 256);

  // --- Phase 3: ctx = bitlinear(t, w_v, b_v), batch-shared weights ---
  for (int b = 0; b < 8; b++)
    ((float4*)cs)[b * 256 + tid] = ((const float4*)tvec)[b * 256 + tid];
  __syncthreads();
  {
    float s2 = scales[2];
    int wv = tid >> 6, lane = tid & 63;
    int o = blockIdx.x * 4 + wv;
    const float4* wr = (const float4*)(w_v + (size_t)o * Dd);
    float acc[8] = {0, 0, 0, 0, 0, 0, 0, 0};
#pragma unroll
    for (int i = 0; i < 4; i++) {
      float4 t4 = tern4(wr[i * 64 + lane], s2);
#pragma unroll
      for (int b = 0; b < 8; b++)
        acc[b] += dot4(((float4*)cs)[b * 256 + i * 64 + lane], t4);
    }
#pragma unroll
    for (int b = 0; b < 8; b++) acc[b] = wred_sum(acc[b]);
    if (lane == 0) {
      float bv = b_v[o];
#pragma unroll
      for (int b = 0; b < 8; b++)
        ctx[(size_t)b * Dd + o] = s2 * acc[b] + bv;
    }
  }
  gridspin(&cnt[5], 256);

  // --- Phase 4: quantize [query, ctx] (redundant per block) + final GEMV ---
  __syncthreads();
  for (int b = 0; b < 8; b++) {
    float4 vq = ((const float4*)(query + (size_t)b * Dd))[tid];
    float4 vc = ((const float4*)(ctx   + (size_t)b * Dd))[tid];
    float am = fmaxf(
        fmaxf(fmaxf(fabsf(vq.x), fabsf(vq.y)), fmaxf(fabsf(vq.z), fabsf(vq.w))),
        fmaxf(fmaxf(fabsf(vc.x), fabsf(vc.y)), fmaxf(fabsf(vc.z), fabsf(vc.w))));
    am = blk_reduce(am, true, red);
    float g = am + EPS;
    float c = 127.0f / g;
    ((float4*)cs)[b * 512 + tid]       = quant4(vq, c);
    ((float4*)cs)[b * 512 + 256 + tid] = quant4(vc, c);
    if (tid == 0) gsh[b] = g;
  }
  __syncthreads();
  {
    float s3 = scales[3];
    int wv = tid >> 6, lane = tid & 63;
    int o = blockIdx.x * 4 + wv;
    const float4* wr = (const float4*)(w_c + (size_t)o * 2 * Dd);
    float acc[8] = {0, 0, 0, 0, 0, 0, 0, 0};
#pragma unroll
    for (int i = 0; i < 8; i++) {
      float4 t4 = tern4(wr[i * 64 + lane], s3);
#pragma unroll
      for (int b = 0; b < 8; b++)
        acc[b] += dot4(((float4*)cs)[b * 512 + i * 64 + lane], t4);
    }
#pragma unroll
    for (int b = 0; b < 8; b++) acc[b] = wred_sum(acc[b]);
    if (lane == 0) {
      float bc = b_c[o];
#pragma unroll
      for (int b = 0; b < 8; b++)
        out[(size_t)b * Dd + o] = s3 * (gsh[b] / 127.0f) * acc[b] + bc;
    }
  }
}

// ---------- launch ----------

extern "C" void kernel_launch(void* const* d_in, const int* in_sizes, int n_in,
                              void* d_out, int out_size, void* d_ws, size_t ws_size,
                              hipStream_t stream)
{
  const float* query = (const float*)d_in[0];
  const float* X     = (const float*)d_in[1];
  const float* w_q   = (const float*)d_in[2];
  const float* b_q   = (const float*)d_in[3];
  const float* w_k   = (const float*)d_in[4];
  const float* b_k   = (const float*)d_in[5];
  const float* w_v   = (const float*)d_in[6];
  const float* b_v   = (const float*)d_in[7];
  const float* w_c   = (const float*)d_in[8];
  const float* b_c   = (const float*)d_in[9];
  float* out = (float*)d_out;
  char* ws = (char*)d_ws;

  size_t off = 0;
  auto alloc = [&](size_t bytes) -> size_t {
    size_t o = off;
    off += (bytes + 255) & ~(size_t)255;
    return o;
  };
  size_t o_cnt    = alloc(256);                 // cnt[0..5]
  size_t o_part   = alloc(256 * sizeof(double));
  size_t o_scales = alloc(4 * sizeof(float));
  size_t o_q      = alloc((size_t)Bb * Dd * 4);
  size_t o_qk     = alloc((size_t)Bb * Dd * 4);
  size_t o_qbk    = alloc(Bb * sizeof(float));
  size_t o_t      = alloc((size_t)Bb * Dd * 4);
  size_t o_ctx    = alloc((size_t)Bb * Dd * 4);
  size_t o_ML     = alloc(Bb * 2 * sizeof(float));
  size_t o_t32    = alloc((size_t)Bb * 32 * Dd * 4);
  size_t o_qkp    = alloc((size_t)NCH * Bb * Dd * 4);
  size_t o_mp     = alloc((size_t)Bb * NWv * 4);
  size_t o_lp     = alloc((size_t)Bb * NWv * 4);
  size_t o_tp     = alloc((size_t)Bb * NWv * Dd * 4);
  (void)ws_size;

  int*    cnt    = (int*)(ws + o_cnt);
  double* part   = (double*)(ws + o_part);
  float*  scales = (float*)(ws + o_scales);
  float*  qv     = (float*)(ws + o_q);
  float*  qk     = (float*)(ws + o_qk);
  float*  qbk    = (float*)(ws + o_qbk);
  float*  tvec   = (float*)(ws + o_t);
  float*  ctx    = (float*)(ws + o_ctx);
  float*  ML     = (float*)(ws + o_ML);
  float*  t32    = (float*)(ws + o_t32);
  float*  qkp    = (float*)(ws + o_qkp);
  float*  mp     = (float*)(ws + o_mp);
  float*  lp     = (float*)(ws + o_lp);
  float*  tp     = (float*)(ws + o_tp);

  hipMemsetAsync(ws + o_cnt, 0, 256, stream);
  k_pre<<<256, 256, 0, stream>>>(query, w_q, b_q, w_k, b_k, w_v, w_c,
                                 part, scales, qv, qkp, qk, qbk, cnt);
  k_pass<<<Bb * NW, 256, 0, stream>>>(X, qk, qbk, mp, lp, tp);
  k_post<<<256, 256, 0, stream>>>(query, mp, lp, tp, w_v, b_v, w_c, b_c,
                                  scales, t32, ML, tvec, ctx, out, cnt);
}

// Round 6
// 140.489 us; speedup vs baseline: 2.1578x; 2.1578x over previous
//
#include <hip/hip_runtime.h>
#include <hip/hip_bf16.h>
#include <math.h>

#define EPS 1e-5f

static constexpr int Bb = 8;
static constexpr int Ss = 8192;
static constexpr int Dd = 1024;      // QD = KD = AD
static constexpr int NW = 64;        // pass blocks per batch
static constexpr int NWv = NW * 4;   // wave partials per batch (256)
static constexpr int TOK = Ss / NWv; // tokens per wave (32)
static constexpr int NCH = 64;       // qk chunk count
static constexpr int RC = Dd / NCH;  // rows per chunk (16)

// ---------- helpers ----------

__device__ __forceinline__ float blk_reduce(float v, bool ismax, volatile float* lds) {
#pragma unroll
  for (int msk = 32; msk; msk >>= 1) {
    float o = __shfl_xor(v, msk);
    v = ismax ? fmaxf(v, o) : (v + o);
  }
  int w = threadIdx.x >> 6;
  __syncthreads();
  if ((threadIdx.x & 63) == 0) lds[w] = v;
  __syncthreads();
  return ismax ? fmaxf(fmaxf(lds[0], lds[1]), fmaxf(lds[2], lds[3]))
               : (lds[0] + lds[1] + lds[2] + lds[3]);
}

__device__ __forceinline__ float wred_max(float v) {
#pragma unroll
  for (int msk = 32; msk; msk >>= 1) v = fmaxf(v, __shfl_xor(v, msk));
  return v;
}

__device__ __forceinline__ float wred_sum(float v) {
#pragma unroll
  for (int msk = 32; msk; msk >>= 1) v += __shfl_xor(v, msk);
  return v;
}

__device__ __forceinline__ float quantf(float x, float c) {
  return fminf(fmaxf(rintf(x * c), -128.f), 127.f);
}

__device__ __forceinline__ float ternf(float w, float s) {
  return fminf(fmaxf(rintf(w / s), -1.f), 1.f);
}

__device__ __forceinline__ float4 tern4(float4 w, float s) {
  return make_float4(ternf(w.x, s), ternf(w.y, s), ternf(w.z, s), ternf(w.w, s));
}

__device__ __forceinline__ float4 quant4(float4 v, float c) {
  return make_float4(quantf(v.x, c), quantf(v.y, c), quantf(v.z, c), quantf(v.w, c));
}

__device__ __forceinline__ float dot4(float4 a, float4 b) {
  return a.x * b.x + a.y * b.y + a.z * b.z + a.w * b.w;
}

// ---------- K1: weight abs-mean scales (last-arriver finalize; no spin) ----------

__global__ __launch_bounds__(256) void k_scales(
    const float* __restrict__ w0, const float* __restrict__ w1,
    const float* __restrict__ w2, const float* __restrict__ w3,
    double* __restrict__ part, float* __restrict__ scales, int* __restrict__ cnt)
{
  int seg = blockIdx.x >> 6;
  int blk = blockIdx.x & 63;
  const float* w = seg == 0 ? w0 : seg == 1 ? w1 : seg == 2 ? w2 : w3;
  int n4 = (seg == 3 ? (1024 * 2048) : (1024 * 1024)) >> 2;
  const float4* w4 = (const float4*)w;
  double acc = 0.0;
  for (int i = blk * 256 + threadIdx.x; i < n4; i += 64 * 256) {
    float4 v = w4[i];
    acc += (double)fabsf(v.x) + (double)fabsf(v.y)
         + (double)fabsf(v.z) + (double)fabsf(v.w);
  }
  __shared__ double sred[256];
  sred[threadIdx.x] = acc;
  __syncthreads();
  for (int s = 128; s > 0; s >>= 1) {
    if (threadIdx.x < s) sred[threadIdx.x] += sred[threadIdx.x + s];
    __syncthreads();
  }
  __shared__ int lastold;
  if (threadIdx.x == 0) {
    part[blockIdx.x] = sred[0];
    __threadfence();
    lastold = atomicAdd(cnt, 1);
  }
  __syncthreads();
  if (lastold == 255) {
    __threadfence();
    if (threadIdx.x < 4) {
      int sg = threadIdx.x;
      double s = 0.0;
      for (int i = 0; i < 64; i++) s += part[sg * 64 + i];
      double n = (sg == 3) ? 2097152.0 : 1048576.0;
      scales[sg] = (float)(s / n) + EPS;
    }
  }
}

// ---------- K2: batch-shared q-GEMV (quantize query + ternary GEMV, w_q once) ----------
// 256 blocks; block handles 4 outputs for ALL 8 batches.

__global__ __launch_bounds__(256) void k_qgemv(
    const float* __restrict__ query, const float* __restrict__ W,
    const float* __restrict__ bias, const float* __restrict__ scales,
    float* __restrict__ out)
{
  __shared__ float qs[Bb * Dd];   // 32 KB quantized query
  __shared__ float red[4];
  __shared__ float gsh[8];
  int tid = threadIdx.x, wv = tid >> 6, lane = tid & 63;
  for (int b = 0; b < 8; b++) {
    float4 v = ((const float4*)(query + (size_t)b * Dd))[tid];
    float am = fmaxf(fmaxf(fabsf(v.x), fabsf(v.y)), fmaxf(fabsf(v.z), fabsf(v.w)));
    am = blk_reduce(am, true, red);
    float g = am + EPS;
    ((float4*)qs)[b * 256 + tid] = quant4(v, 127.0f / g);
    if (tid == 0) gsh[b] = g;
  }
  __syncthreads();
  float s0 = scales[0];
  int o = blockIdx.x * 4 + wv;
  const float4* wr = (const float4*)(W + (size_t)o * Dd);
  float acc[8] = {0, 0, 0, 0, 0, 0, 0, 0};
#pragma unroll
  for (int i = 0; i < 4; i++) {
    float4 t4 = tern4(wr[i * 64 + lane], s0);
#pragma unroll
    for (int b = 0; b < 8; b++)
      acc[b] += dot4(((float4*)qs)[b * 256 + i * 64 + lane], t4);
  }
#pragma unroll
  for (int b = 0; b < 8; b++) acc[b] = wred_sum(acc[b]);
  if (lane == 0) {
    float bq = bias[o];
#pragma unroll
    for (int b = 0; b < 8; b++)
      out[(size_t)b * Dd + o] = s0 * (gsh[b] / 127.0f) * acc[b] + bq;
  }
}

// ---------- K3: qk = s_k * (q @ tern(Wk)) with fused comb via 64-block spin ----------

__global__ __launch_bounds__(256) void k_qk(
    const float* __restrict__ q, const float* __restrict__ Wk,
    const float* __restrict__ bk, const float* __restrict__ scales,
    float* __restrict__ part, float* __restrict__ qk, float* __restrict__ qdotbk,
    int* __restrict__ cnt)
{
  __shared__ float qs[Bb * RC];
  int ch = blockIdx.x;
  int a0 = ch * RC;
  int tid = threadIdx.x;
  if (tid < Bb * RC) {
    int b = tid / RC, a = tid - b * RC;
    qs[tid] = q[(size_t)b * Dd + a0 + a];
  }
  __syncthreads();
  float s = scales[1];
  float4 acc[Bb];
#pragma unroll
  for (int b = 0; b < Bb; b++) acc[b] = make_float4(0.f, 0.f, 0.f, 0.f);
  const float4* Wr = (const float4*)(Wk + (size_t)a0 * Dd);
  for (int i = 0; i < RC; i++) {
    float4 t4 = tern4(Wr[(size_t)i * 256 + tid], s);
#pragma unroll
    for (int b = 0; b < Bb; b++) {
      float qb = qs[b * RC + i];
      acc[b].x += qb * t4.x; acc[b].y += qb * t4.y;
      acc[b].z += qb * t4.z; acc[b].w += qb * t4.w;
    }
  }
#pragma unroll
  for (int b = 0; b < Bb; b++)
    ((float4*)part)[((size_t)ch * Bb + b) * 256 + tid] = acc[b];

  // spin barrier across 64 blocks (well under machine occupancy -> safe & fast)
  __threadfence();
  if (tid == 0) {
    atomicAdd(cnt, 1);
    while (__hip_atomic_load(cnt, __ATOMIC_ACQUIRE, __HIP_MEMORY_SCOPE_AGENT) < NCH)
      __builtin_amdgcn_s_sleep(8);
  }
  __syncthreads();
  __threadfence();

  // phase 2: block = (b, d-chunk of 128 floats = 32 float4)
  int b = blockIdx.x >> 3, dc = blockIdx.x & 7;
  if (tid < 32) {
    int d4 = dc * 32 + tid;
    float4 a = make_float4(0.f, 0.f, 0.f, 0.f);
    for (int k = 0; k < NCH; k++) {
      float4 p = ((const float4*)part)[((size_t)k * Bb + b) * 256 + d4];
      a.x += p.x; a.y += p.y; a.z += p.z; a.w += p.w;
    }
    ((float4*)qk)[(size_t)b * 256 + d4] = make_float4(s * a.x, s * a.y, s * a.z, s * a.w);
  } else if (dc == 0 && tid >= 64 && tid < 128) {
    int lane = tid - 64;
    float p = 0.f;
    for (int a2 = lane; a2 < Dd; a2 += 64) p += q[(size_t)b * Dd + a2] * bk[a2];
    p = wred_sum(p);
    if (lane == 0) qdotbk[b] = p;
  }
}

// ---------- K4: fused streaming pass, one WAVE per token, defer-max ----------

__global__ __launch_bounds__(256) void k_pass(
    const float* __restrict__ X, const float* __restrict__ qk,
    const float* __restrict__ qdotbk,
    float* __restrict__ m_part, float* __restrict__ l_part,
    float* __restrict__ t_part)
{
  int b    = blockIdx.x >> 6;
  int wg   = blockIdx.x & 63;
  int wv   = threadIdx.x >> 6;
  int lane = threadIdx.x & 63;
  int widx = wg * 4 + wv;
  int s0   = widx * TOK;

  const float4* qkb = (const float4*)(qk + (size_t)b * Dd);
  float4 qv0 = qkb[lane], qv1 = qkb[64 + lane], qv2 = qkb[128 + lane], qv3 = qkb[192 + lane];
  float qb = qdotbk[b];
  const float4* Xw = (const float4*)(X + ((size_t)b * Ss + s0) * Dd);

  float m = -INFINITY, l = 0.f;
  float4 a0 = make_float4(0,0,0,0), a1 = a0, a2 = a0, a3 = a0;

  float4 x0 = Xw[lane], x1 = Xw[64 + lane], x2 = Xw[128 + lane], x3 = Xw[192 + lane];
  for (int i = 0; i < TOK; i++) {
    size_t nb = (size_t)((i + 1 < TOK) ? i + 1 : i) * 256;
    float4 n0 = Xw[nb + lane], n1 = Xw[nb + 64 + lane],
           n2 = Xw[nb + 128 + lane], n3 = Xw[nb + 192 + lane];

    float am = fmaxf(
      fmaxf(fmaxf(fmaxf(fabsf(x0.x), fabsf(x0.y)), fmaxf(fabsf(x0.z), fabsf(x0.w))),
            fmaxf(fmaxf(fabsf(x1.x), fabsf(x1.y)), fmaxf(fabsf(x1.z), fabsf(x1.w)))),
      fmaxf(fmaxf(fmaxf(fabsf(x2.x), fabsf(x2.y)), fmaxf(fabsf(x2.z), fabsf(x2.w))),
            fmaxf(fmaxf(fabsf(x3.x), fabsf(x3.y)), fmaxf(fabsf(x3.z), fabsf(x3.w)))));
    am = wred_max(am);
    float g = am + EPS;
    float c = 127.0f / g;
    float gi = g / 127.0f;

    float q00 = quantf(x0.x, c), q01 = quantf(x0.y, c), q02 = quantf(x0.z, c), q03 = quantf(x0.w, c);
    float q10 = quantf(x1.x, c), q11 = quantf(x1.y, c), q12 = quantf(x1.z, c), q13 = quantf(x1.w, c);
    float q20 = quantf(x2.x, c), q21 = quantf(x2.y, c), q22 = quantf(x2.z, c), q23 = quantf(x2.w, c);
    float q30 = quantf(x3.x, c), q31 = quantf(x3.y, c), q32 = quantf(x3.z, c), q33 = quantf(x3.w, c);

    float dt = q00 * qv0.x + q01 * qv0.y + q02 * qv0.z + q03 * qv0.w
             + q10 * qv1.x + q11 * qv1.y + q12 * qv1.z + q13 * qv1.w
             + q20 * qv2.x + q21 * qv2.y + q22 * qv2.z + q23 * qv2.w
             + q30 * qv3.x + q31 * qv3.y + q32 * qv3.z + q33 * qv3.w;
    dt = wred_sum(dt);

    float score = (dt * gi + qb) * 0.03125f;   // / sqrt(1024)
    if (score <= m) {                          // wave-uniform
      float p  = expf(score - m);
      l += p;
      float cf = p * gi;
      a0.x += cf * q00; a0.y += cf * q01; a0.z += cf * q02; a0.w += cf * q03;
      a1.x += cf * q10; a1.y += cf * q11; a1.z += cf * q12; a1.w += cf * q13;
      a2.x += cf * q20; a2.y += cf * q21; a2.z += cf * q22; a2.w += cf * q23;
      a3.x += cf * q30; a3.y += cf * q31; a3.z += cf * q32; a3.w += cf * q33;
    } else {
      float scl = expf(m - score);
      l = l * scl + 1.0f;
      float cf = gi;
      a0.x = a0.x * scl + cf * q00; a0.y = a0.y * scl + cf * q01;
      a0.z = a0.z * scl + cf * q02; a0.w = a0.w * scl + cf * q03;
      a1.x = a1.x * scl + cf * q10; a1.y = a1.y * scl + cf * q11;
      a1.z = a1.z * scl + cf * q12; a1.w = a1.w * scl + cf * q13;
      a2.x = a2.x * scl + cf * q20; a2.y = a2.y * scl + cf * q21;
      a2.z = a2.z * scl + cf * q22; a2.w = a2.w * scl + cf * q23;
      a3.x = a3.x * scl + cf * q30; a3.y = a3.y * scl + cf * q31;
      a3.z = a3.z * scl + cf * q32; a3.w = a3.w * scl + cf * q33;
      m = score;
    }
    x0 = n0; x1 = n1; x2 = n2; x3 = n3;
  }

  size_t pidx = (size_t)b * NWv + widx;
  float4* tpw = (float4*)t_part + (size_t)pidx * 256;
  tpw[lane] = a0; tpw[64 + lane] = a1; tpw[128 + lane] = a2; tpw[192 + lane] = a3;
  if (lane == 0) { m_part[pidx] = m; l_part[pidx] = l; }
}

// ---------- K5: fused combine (redundant M,L; tree; last-arriver per batch) ----------

__global__ __launch_bounds__(256) void k_comb(
    const float* __restrict__ m_part, const float* __restrict__ l_part,
    const float* __restrict__ t_part, float* __restrict__ t16,
    float* __restrict__ t, int* __restrict__ cnt)
{
  __shared__ float red[4];
  int b = blockIdx.x >> 4, k = blockIdx.x & 15;
  int tid = threadIdx.x;
  float mi = m_part[(size_t)b * NWv + tid];
  float M = blk_reduce(mi, true, red);
  float li = l_part[(size_t)b * NWv + tid] * expf(mi - M);
  float L = blk_reduce(li, false, red);

  float4 acc = make_float4(0,0,0,0);
  for (int i = 0; i < 16; i++) {
    size_t pi = (size_t)b * NWv + k * 16 + i;
    float w = expf(m_part[pi] - M);
    float4 tp = ((const float4*)t_part)[pi * 256 + tid];
    acc.x += w * tp.x; acc.y += w * tp.y; acc.z += w * tp.z; acc.w += w * tp.w;
  }
  ((float4*)t16)[((size_t)(b * 16 + k)) * 256 + tid] = acc;

  __shared__ int lastold;
  if (tid == 0) {
    __threadfence();
    lastold = atomicAdd(&cnt[b], 1);
  }
  __syncthreads();
  if (lastold == 15) {
    __threadfence();
    float invL = 1.0f / L;
    float4 a = make_float4(0,0,0,0);
    for (int kk = 0; kk < 16; kk++) {
      float4 v = ((const float4*)t16)[((size_t)(b * 16 + kk)) * 256 + tid];
      a.x += v.x; a.y += v.y; a.z += v.z; a.w += v.w;
    }
    ((float4*)t)[(size_t)b * 256 + tid] =
        make_float4(a.x * invL, a.y * invL, a.z * invL, a.w * invL);
  }
}

// ---------- K6: batch-shared v-GEMV (ctx = bitlinear(t, w_v, b_v), w_v once) ----------

__global__ __launch_bounds__(256) void k_vgemv(
    const float* __restrict__ act, const float* __restrict__ W,
    const float* __restrict__ bias, const float* __restrict__ scales,
    float* __restrict__ out)
{
  __shared__ float cs[Bb * Dd];   // 32 KB
  int tid = threadIdx.x, wv = tid >> 6, lane = tid & 63;
  for (int b = 0; b < 8; b++)
    ((float4*)cs)[b * 256 + tid] = ((const float4*)act)[b * 256 + tid];
  __syncthreads();
  float s2 = scales[2];
  int o = blockIdx.x * 4 + wv;
  const float4* wr = (const float4*)(W + (size_t)o * Dd);
  float acc[8] = {0, 0, 0, 0, 0, 0, 0, 0};
#pragma unroll
  for (int i = 0; i < 4; i++) {
    float4 t4 = tern4(wr[i * 64 + lane], s2);
#pragma unroll
    for (int b = 0; b < 8; b++)
      acc[b] += dot4(((float4*)cs)[b * 256 + i * 64 + lane], t4);
  }
#pragma unroll
  for (int b = 0; b < 8; b++) acc[b] = wred_sum(acc[b]);
  if (lane == 0) {
    float bv = bias[o];
#pragma unroll
    for (int b = 0; b < 8; b++)
      out[(size_t)b * Dd + o] = s2 * acc[b] + bv;
  }
}

// ---------- K7: batch-shared final GEMV (quantize [query,ctx] + w_c once) ----------

__global__ __launch_bounds__(256) void k_final(
    const float* __restrict__ query, const float* __restrict__ ctx,
    const float* __restrict__ W, const float* __restrict__ bias,
    const float* __restrict__ scales, float* __restrict__ out)
{
  __shared__ float cs[Bb * 2 * Dd];   // 64 KB quantized [query, ctx]
  __shared__ float red[4];
  __shared__ float gsh[8];
  int tid = threadIdx.x, wv = tid >> 6, lane = tid & 63;
  for (int b = 0; b < 8; b++) {
    float4 vq = ((const float4*)(query + (size_t)b * Dd))[tid];
    float4 vc = ((const float4*)(ctx   + (size_t)b * Dd))[tid];
    float am = fmaxf(
        fmaxf(fmaxf(fabsf(vq.x), fabsf(vq.y)), fmaxf(fabsf(vq.z), fabsf(vq.w))),
        fmaxf(fmaxf(fabsf(vc.x), fabsf(vc.y)), fmaxf(fabsf(vc.z), fabsf(vc.w))));
    am = blk_reduce(am, true, red);
    float g = am + EPS;
    float c = 127.0f / g;
    ((float4*)cs)[b * 512 + tid]       = quant4(vq, c);
    ((float4*)cs)[b * 512 + 256 + tid] = quant4(vc, c);
    if (tid == 0) gsh[b] = g;
  }
  __syncthreads();
  float s3 = scales[3];
  int o = blockIdx.x * 4 + wv;
  const float4* wr = (const float4*)(W + (size_t)o * 2 * Dd);
  float acc[8] = {0, 0, 0, 0, 0, 0, 0, 0};
#pragma unroll
  for (int i = 0; i < 8; i++) {
    float4 t4 = tern4(wr[i * 64 + lane], s3);
#pragma unroll
    for (int b = 0; b < 8; b++)
      acc[b] += dot4(((float4*)cs)[b * 512 + i * 64 + lane], t4);
  }
#pragma unroll
  for (int b = 0; b < 8; b++) acc[b] = wred_sum(acc[b]);
  if (lane == 0) {
    float bc = bias[o];
#pragma unroll
    for (int b = 0; b < 8; b++)
      out[(size_t)b * Dd + o] = s3 * (gsh[b] / 127.0f) * acc[b] + bc;
  }
}

// ---------- launch ----------

extern "C" void kernel_launch(void* const* d_in, const int* in_sizes, int n_in,
                              void* d_out, int out_size, void* d_ws, size_t ws_size,
                              hipStream_t stream)
{
  const float* query = (const float*)d_in[0];
  const float* X     = (const float*)d_in[1];
  const float* w_q   = (const float*)d_in[2];
  const float* b_q   = (const float*)d_in[3];
  const float* w_k   = (const float*)d_in[4];
  const float* b_k   = (const float*)d_in[5];
  const float* w_v   = (const float*)d_in[6];
  const float* b_v   = (const float*)d_in[7];
  const float* w_c   = (const float*)d_in[8];
  const float* b_c   = (const float*)d_in[9];
  float* out = (float*)d_out;
  char* ws = (char*)d_ws;

  size_t off = 0;
  auto alloc = [&](size_t bytes) -> size_t {
    size_t o = off;
    off += (bytes + 255) & ~(size_t)255;
    return o;
  };
  size_t o_cnt    = alloc(256);                 // [0]=scales, [1]=qk, [2..9]=comb
  size_t o_part   = alloc(256 * sizeof(double));
  size_t o_scales = alloc(4 * sizeof(float));
  size_t o_q      = alloc((size_t)Bb * Dd * 4);
  size_t o_qk     = alloc((size_t)Bb * Dd * 4);
  size_t o_qbk    = alloc(Bb * sizeof(float));
  size_t o_t      = alloc((size_t)Bb * Dd * 4);
  size_t o_ctx    = alloc((size_t)Bb * Dd * 4);
  size_t o_t16    = alloc((size_t)Bb * 16 * Dd * 4);
  size_t o_qkp    = alloc((size_t)NCH * Bb * Dd * 4);
  size_t o_mp     = alloc((size_t)Bb * NWv * 4);
  size_t o_lp     = alloc((size_t)Bb * NWv * 4);
  size_t o_tp     = alloc((size_t)Bb * NWv * Dd * 4);
  (void)ws_size;

  int*    cnt    = (int*)(ws + o_cnt);
  double* part   = (double*)(ws + o_part);
  float*  scales = (float*)(ws + o_scales);
  float*  qv     = (float*)(ws + o_q);
  float*  qk     = (float*)(ws + o_qk);
  float*  qbk    = (float*)(ws + o_qbk);
  float*  tvec   = (float*)(ws + o_t);
  float*  ctx    = (float*)(ws + o_ctx);
  float*  t16    = (float*)(ws + o_t16);
  float*  qkp    = (float*)(ws + o_qkp);
  float*  mp     = (float*)(ws + o_mp);
  float*  lp     = (float*)(ws + o_lp);
  float*  tp     = (float*)(ws + o_tp);

  hipMemsetAsync(ws + o_cnt, 0, 256, stream);
  k_scales<<<256, 256, 0, stream>>>(w_q, w_k, w_v, w_c, part, scales, &cnt[0]);
  k_qgemv<<<256, 256, 0, stream>>>(query, w_q, b_q, scales, qv);
  k_qk<<<NCH, 256, 0, stream>>>(qv, w_k, b_k, scales, qkp, qk, qbk, &cnt[1]);
  k_pass<<<Bb * NW, 256, 0, stream>>>(X, qk, qbk, mp, lp, tp);
  k_comb<<<Bb * 16, 256, 0, stream>>>(mp, lp, tp, t16, tvec, &cnt[2]);
  k_vgemv<<<256, 256, 0, stream>>>(tvec, w_v, b_v, scales, ctx);
  k_final<<<256, 256, 0, stream>>>(query, ctx, w_c, b_c, scales, out);
}